// Round 1
// baseline (492.531 us; speedup 1.0000x reference)
//
#include <hip/hip_runtime.h>

#define Bb 32
#define Nn 4096
#define Dd 256
#define Hh 256
#define TM 64
#define KS 16
#define NSTEPS 32   // K-dim 512 total (Q:256 then K:256) in steps of 16
#define NCH 32
#define CHUNK 128   // Nn / NCH

__device__ __forceinline__ float fast_tanhf(float x) {
    // tanh(x) = 1 - 2/(exp(2x)+1); saturates correctly for |x| large (no NaN)
    float e = __expf(2.0f * x);
    return 1.0f - 2.0f / (e + 1.0f);
}

// ---------------------------------------------------------------------------
// Kernel A: scores[b*N+n] = sum_h Wv[h] * tanh( Q_row·Wq[h,:] + K_row·Wk[h,:] )
// One block = 64 rows x all 256 h (full-H per block -> no atomics, deterministic).
// Treated as GEMM M=131072, K=512 (Q half then K half), N=256.
// ---------------------------------------------------------------------------
__global__ __launch_bounds__(256) void scores_kernel(
    const float* __restrict__ Q, const float* __restrict__ Kmat,
    const float* __restrict__ Wq, const float* __restrict__ Wk,
    const float* __restrict__ Wv, float* __restrict__ scores)
{
    __shared__ float Al[2][KS][TM];     // A tile, k-major: Al[kk][row]
    __shared__ float Bl[2][KS][Hh];     // B tile, k-major: Bl[kk][h]
    __shared__ float red[TM][17];

    const int tid = threadIdx.x;
    const int tx = tid & 15;            // h-group
    const int ty = tid >> 4;            // row-group
    const size_t row0 = (size_t)blockIdx.x * TM;

    float acc[4][16];
#pragma unroll
    for (int i = 0; i < 4; ++i)
#pragma unroll
        for (int j = 0; j < 16; ++j) acc[i][j] = 0.0f;

    auto stage = [&](int buf, int s) {
        const float* Asrc = (s < 16) ? Q : Kmat;
        const float* Bsrc = (s < 16) ? Wq : Wk;
        const int k0 = (s & 15) * KS;
        {   // A: 64 rows x 16 k  (1 float4 per thread), store transposed
            const int row = tid >> 2;
            const int kf4 = (tid & 3) * 4;
            const float4 v = *(const float4*)(Asrc + (row0 + row) * Dd + k0 + kf4);
            Al[buf][kf4 + 0][row] = v.x;
            Al[buf][kf4 + 1][row] = v.y;
            Al[buf][kf4 + 2][row] = v.z;
            Al[buf][kf4 + 3][row] = v.w;
        }
#pragma unroll
        for (int i = 0; i < 4; ++i) {   // B: 256 h x 16 k (4 float4 per thread)
            const int f4 = tid + i * 256;
            const int h = f4 >> 2;
            const int kf4 = (f4 & 3) * 4;
            const float4 v = *(const float4*)(Bsrc + h * Dd + k0 + kf4);
            Bl[buf][kf4 + 0][h] = v.x;
            Bl[buf][kf4 + 1][h] = v.y;
            Bl[buf][kf4 + 2][h] = v.z;
            Bl[buf][kf4 + 3][h] = v.w;
        }
    };

    auto compute = [&](int buf) {
#pragma unroll
        for (int kk = 0; kk < KS; ++kk) {
            const float4 a4 = *(const float4*)&Al[buf][kk][ty * 4];
            const float av[4] = {a4.x, a4.y, a4.z, a4.w};
#pragma unroll
            for (int g = 0; g < 4; ++g) {
                const float4 b4 = *(const float4*)&Bl[buf][kk][tx * 4 + g * 64];
                const float bw[4] = {b4.x, b4.y, b4.z, b4.w};
#pragma unroll
                for (int i = 0; i < 4; ++i)
#pragma unroll
                    for (int j = 0; j < 4; ++j)
                        acc[i][g * 4 + j] = fmaf(av[i], bw[j], acc[i][g * 4 + j]);
            }
        }
    };

    stage(0, 0);
    for (int s = 0; s < NSTEPS; ++s) {
        __syncthreads();
        if (s + 1 < NSTEPS) stage((s + 1) & 1, s + 1);
        compute(s & 1);
    }

    // epilogue: tanh, weight by Wv, reduce over h (fixed order -> deterministic)
    float part[4] = {0.f, 0.f, 0.f, 0.f};
#pragma unroll
    for (int g = 0; g < 4; ++g)
#pragma unroll
        for (int j = 0; j < 4; ++j) {
            const int col = tx * 4 + g * 64 + j;
            const float w = Wv[col];
#pragma unroll
            for (int i = 0; i < 4; ++i)
                part[i] += fast_tanhf(acc[i][g * 4 + j]) * w;
        }
    __syncthreads();   // compute done reading LDS; (red is separate, but keep ordering simple)
#pragma unroll
    for (int i = 0; i < 4; ++i) red[ty * 4 + i][tx] = part[i];
    __syncthreads();
    if (tid < TM) {
        float ssum = 0.f;
#pragma unroll
        for (int x = 0; x < 16; ++x) ssum += red[tid][x];
        scores[row0 + tid] = ssum;
    }
}

// ---------------------------------------------------------------------------
// Kernel B1: per-b max + first-index argmax + sum(exp). Writes argmax output.
// ---------------------------------------------------------------------------
__global__ __launch_bounds__(256) void softmax_reduce_kernel(
    const float* __restrict__ scores, float* __restrict__ mbuf,
    float* __restrict__ zbuf, float* __restrict__ out)
{
    __shared__ float sv[256];
    __shared__ int si[256];
    const int b = blockIdx.x;
    const int tid = threadIdx.x;
    const float* sc = scores + (size_t)b * Nn;

    float best = -1e30f; int bi = 0;
    for (int j = 0; j < Nn / 256; ++j) {
        const int n = tid + j * 256;
        const float v = sc[n];
        if (v > best) { best = v; bi = n; }   // strict > keeps first occurrence
    }
    sv[tid] = best; si[tid] = bi;
    __syncthreads();
    for (int off = 128; off > 0; off >>= 1) {
        if (tid < off) {
            const float v2 = sv[tid + off]; const int i2 = si[tid + off];
            if (v2 > sv[tid] || (v2 == sv[tid] && i2 < si[tid])) { sv[tid] = v2; si[tid] = i2; }
        }
        __syncthreads();
    }
    const float m = sv[0];
    const int amax = si[0];
    __syncthreads();   // everyone has read sv[0]/si[0] before reuse

    float s = 0.f;
    for (int j = 0; j < Nn / 256; ++j) s += __expf(sc[tid + j * 256] - m);
    sv[tid] = s;
    __syncthreads();
    for (int off = 128; off > 0; off >>= 1) {
        if (tid < off) sv[tid] += sv[tid + off];
        __syncthreads();
    }
    if (tid == 0) {
        mbuf[b] = m;
        zbuf[b] = sv[0];
        out[(size_t)Bb * Dd + b] = (float)amax;   // argmax output, as float
    }
}

// ---------------------------------------------------------------------------
// Kernel B2: partial out over n-chunks (no atomics; fixed-order accumulation)
// grid = (NCH, Bb)
// ---------------------------------------------------------------------------
__global__ __launch_bounds__(256) void partial_kernel(
    const float* __restrict__ V, const float* __restrict__ scores,
    const float* __restrict__ mbuf, float* __restrict__ part)
{
    __shared__ float e[CHUNK];
    const int c = blockIdx.x;
    const int b = blockIdx.y;
    const int tid = threadIdx.x;
    const float m = mbuf[b];
    if (tid < CHUNK)
        e[tid] = __expf(scores[(size_t)b * Nn + (size_t)c * CHUNK + tid] - m);
    __syncthreads();

    const float* vp = V + ((size_t)b * Nn + (size_t)c * CHUNK) * Dd + tid;
    float a0 = 0.f, a1 = 0.f, a2 = 0.f, a3 = 0.f;
    for (int n = 0; n < CHUNK; n += 4) {
        a0 = fmaf(e[n + 0], vp[(size_t)(n + 0) * Dd], a0);
        a1 = fmaf(e[n + 1], vp[(size_t)(n + 1) * Dd], a1);
        a2 = fmaf(e[n + 2], vp[(size_t)(n + 2) * Dd], a2);
        a3 = fmaf(e[n + 3], vp[(size_t)(n + 3) * Dd], a3);
    }
    part[((size_t)b * NCH + c) * Dd + tid] = ((a0 + a1) + (a2 + a3));
}

// ---------------------------------------------------------------------------
// Kernel C: out[b,d] = (sum_c part[b,c,d]) / Z[b]
// ---------------------------------------------------------------------------
__global__ __launch_bounds__(256) void finalize_kernel(
    const float* __restrict__ part, const float* __restrict__ zbuf,
    float* __restrict__ out)
{
    const int b = blockIdx.x;
    const int tid = threadIdx.x;
    float s = 0.f;
#pragma unroll
    for (int c = 0; c < NCH; ++c) s += part[((size_t)b * NCH + c) * Dd + tid];
    out[(size_t)b * Dd + tid] = s / zbuf[b];
}

extern "C" void kernel_launch(void* const* d_in, const int* in_sizes, int n_in,
                              void* d_out, int out_size, void* d_ws, size_t ws_size,
                              hipStream_t stream) {
    const float* Q  = (const float*)d_in[0];
    const float* K  = (const float*)d_in[1];
    const float* V  = (const float*)d_in[2];
    const float* Wq = (const float*)d_in[3];
    const float* Wk = (const float*)d_in[4];
    const float* Wv = (const float*)d_in[5];
    float* out = (float*)d_out;

    // workspace layout (floats): scores[B*N] | m[B] | Z[B] | part[B*NCH*D]
    float* scores = (float*)d_ws;
    float* mbuf   = scores + (size_t)Bb * Nn;
    float* zbuf   = mbuf + Bb;
    float* part   = zbuf + Bb;

    scores_kernel<<<dim3((Bb * Nn) / TM), dim3(256), 0, stream>>>(Q, K, Wq, Wk, Wv, scores);
    softmax_reduce_kernel<<<dim3(Bb), dim3(256), 0, stream>>>(scores, mbuf, zbuf, out);
    partial_kernel<<<dim3(NCH, Bb), dim3(256), 0, stream>>>(V, scores, mbuf, part);
    finalize_kernel<<<dim3(Bb), dim3(256), 0, stream>>>(part, zbuf, out);
}

// Round 2
// 192.614 us; speedup vs baseline: 2.5571x; 2.5571x over previous
//
#include <hip/hip_runtime.h>

#define Bb 32
#define Nn 4096
#define Dd 256
#define Hh 256
#define NCH 32
#define CHUNK 128
#define KSTEPS 16   // K = 512 (Q:256 then K:256), steps of 32

typedef __attribute__((ext_vector_type(8))) short bf16x8;
typedef __attribute__((ext_vector_type(4))) float f32x4;

__device__ __forceinline__ unsigned short bf16_rtn(float x) {
    unsigned int u = __float_as_uint(x);
    u += 0x7FFF + ((u >> 16) & 1);
    return (unsigned short)(u >> 16);
}
__device__ __forceinline__ float bf16_to_f(unsigned short b) {
    return __uint_as_float(((unsigned int)b) << 16);
}
__device__ __forceinline__ float fast_tanhf(float x) {
    float e = __expf(2.0f * x);
    return 1.0f - 2.0f / (e + 1.0f);
}

// ---------------------------------------------------------------------------
// Prep: split Wcat = [Wq ; Wk] (H=256 rows, K=512 cols) into hi/lo bf16 blobs
// in fragment-linear order: blob[s][j][l][e] = Wcat[j*16+(l&15)][s*32+(l>>4)*8+e]
// 16384 threads, 8 elements each.
// ---------------------------------------------------------------------------
__global__ __launch_bounds__(256) void prep_w_kernel(
    const float* __restrict__ Wq, const float* __restrict__ Wk,
    short* __restrict__ Wh, short* __restrict__ Wl)
{
    const int g = blockIdx.x * 256 + threadIdx.x;      // [0, 16384)
    const int s = g >> 10;
    const int j = (g >> 6) & 15;
    const int l = g & 63;
    const int n = j * 16 + (l & 15);
    const int k = s * 32 + (l >> 4) * 8;
    const float* src = (k < 256) ? (Wq + n * 256 + k) : (Wk + n * 256 + (k - 256));
    const f32x4 v0 = *(const f32x4*)src;
    const f32x4 v1 = *(const f32x4*)(src + 4);
    float xs[8] = {v0.x, v0.y, v0.z, v0.w, v1.x, v1.y, v1.z, v1.w};
    bf16x8 h8, l8;
#pragma unroll
    for (int e = 0; e < 8; ++e) {
        unsigned short hb = bf16_rtn(xs[e]);
        float rem = xs[e] - bf16_to_f(hb);
        h8[e] = (short)hb;
        l8[e] = (short)bf16_rtn(rem);
    }
    *(bf16x8*)&Wh[(size_t)g * 8] = h8;
    *(bf16x8*)&Wl[(size_t)g * 8] = l8;
}

// ---------------------------------------------------------------------------
// Scores via split-bf16 MFMA. Block = 64 rows x 256 h, 4 waves (wave w owns
// cols [64w, 64w+64)). A staged in LDS fragment-linear (hi/lo, double-buffered);
// B frags loaded global->VGPR from prep blobs (L2-resident).
// ---------------------------------------------------------------------------
__global__ __launch_bounds__(256, 3) void scores_mfma_kernel(
    const float* __restrict__ Q, const float* __restrict__ Kmat,
    const short* __restrict__ Wh, const short* __restrict__ Wl,
    const float* __restrict__ Wv, float* __restrict__ scores)
{
    __shared__ short Ah[2][4 * 64 * 8];   // [buf][m][lane][e] hi
    __shared__ short Al[2][4 * 64 * 8];   // lo
    __shared__ float red[4][64];

    const int tid = threadIdx.x;
    const int lane = tid & 63;
    const int wave = tid >> 6;
    const size_t row0 = (size_t)blockIdx.x * 64;

    f32x4 acc[4][4];
#pragma unroll
    for (int m = 0; m < 4; ++m)
#pragma unroll
        for (int n = 0; n < 4; ++n) acc[m][n] = (f32x4){0.f, 0.f, 0.f, 0.f};

    float wv[4];
#pragma unroll
    for (int n = 0; n < 4; ++n) wv[n] = Wv[wave * 64 + n * 16 + (lane & 15)];

    // A staging map: thread t -> (m = t>>6, l = t&63): row = m*16+(l&15),
    // kchunk = (l>>4)*8. LDS write at t*8 (fragment-linear; lane-contiguous).
    const int srow = (tid >> 6) * 16 + (tid & 15);
    const int skb = ((tid >> 4) & 3) * 8;

    auto stageA = [&](int buf, int s) {
        const float* Asrc = (s < 8) ? Q : Kmat;
        const int k0 = (s & 7) * 32;
        const float* p = Asrc + (row0 + srow) * Dd + k0 + skb;
        const f32x4 v0 = *(const f32x4*)p;
        const f32x4 v1 = *(const f32x4*)(p + 4);
        float xs[8] = {v0.x, v0.y, v0.z, v0.w, v1.x, v1.y, v1.z, v1.w};
        bf16x8 h8, l8;
#pragma unroll
        for (int e = 0; e < 8; ++e) {
            unsigned short hb = bf16_rtn(xs[e]);
            float rem = xs[e] - bf16_to_f(hb);
            h8[e] = (short)hb;
            l8[e] = (short)bf16_rtn(rem);
        }
        *(bf16x8*)&Ah[buf][tid * 8] = h8;
        *(bf16x8*)&Al[buf][tid * 8] = l8;
    };

    stageA(0, 0);
    __syncthreads();

    for (int s = 0; s < KSTEPS; ++s) {
        const int cur = s & 1;
        if (s + 1 < KSTEPS) stageA(cur ^ 1, s + 1);

        // A frags from LDS (conflict-free: address = (m*64+lane)*16B)
        bf16x8 ah[4], al[4];
#pragma unroll
        for (int m = 0; m < 4; ++m) {
            ah[m] = *(const bf16x8*)&Ah[cur][(m * 64 + lane) * 8];
            al[m] = *(const bf16x8*)&Al[cur][(m * 64 + lane) * 8];
        }
#pragma unroll
        for (int n = 0; n < 4; ++n) {
            const size_t boff = ((size_t)(s * 16 + wave * 4 + n) * 64 + lane) * 8;
            const bf16x8 bh = *(const bf16x8*)(Wh + boff);
            const bf16x8 bl = *(const bf16x8*)(Wl + boff);
#pragma unroll
            for (int m = 0; m < 4; ++m) {
                acc[m][n] = __builtin_amdgcn_mfma_f32_16x16x32_bf16(ah[m], bh, acc[m][n], 0, 0, 0);
                acc[m][n] = __builtin_amdgcn_mfma_f32_16x16x32_bf16(ah[m], bl, acc[m][n], 0, 0, 0);
                acc[m][n] = __builtin_amdgcn_mfma_f32_16x16x32_bf16(al[m], bh, acc[m][n], 0, 0, 0);
            }
        }
        __syncthreads();
    }

    // Epilogue: score_row += Wv[col] * tanh(acc). C/D layout: col = lane&15,
    // row = m*16 + (lane>>4)*4 + r. Reduce across the 16 cols held by lanes
    // sharing (lane>>4), then across waves via LDS. Fixed order, deterministic.
    const int q = lane >> 4;
    float rp[4][4];
#pragma unroll
    for (int m = 0; m < 4; ++m)
#pragma unroll
        for (int r = 0; r < 4; ++r) {
            float v = 0.f;
#pragma unroll
            for (int n = 0; n < 4; ++n)
                v += wv[n] * fast_tanhf(acc[m][n][r]);
            rp[m][r] = v;
        }
#pragma unroll
    for (int mask = 1; mask <= 8; mask <<= 1)
#pragma unroll
        for (int m = 0; m < 4; ++m)
#pragma unroll
            for (int r = 0; r < 4; ++r)
                rp[m][r] += __shfl_xor(rp[m][r], mask, 64);

    if ((lane & 15) == 0) {
#pragma unroll
        for (int m = 0; m < 4; ++m)
#pragma unroll
            for (int r = 0; r < 4; ++r)
                red[wave][m * 16 + q * 4 + r] = rp[m][r];
    }
    __syncthreads();
    if (tid < 64)
        scores[row0 + tid] = red[0][tid] + red[1][tid] + red[2][tid] + red[3][tid];
}

// ---------------------------------------------------------------------------
// Per-b max + first-index argmax + sum(exp). Writes argmax output.
// ---------------------------------------------------------------------------
__global__ __launch_bounds__(256) void softmax_reduce_kernel(
    const float* __restrict__ scores, float* __restrict__ mbuf,
    float* __restrict__ zbuf, float* __restrict__ out)
{
    __shared__ float sv[256];
    __shared__ int si[256];
    const int b = blockIdx.x;
    const int tid = threadIdx.x;
    const float* sc = scores + (size_t)b * Nn;

    float best = -1e30f; int bi = 0;
    for (int j = 0; j < Nn / 256; ++j) {
        const int n = tid + j * 256;
        const float v = sc[n];
        if (v > best) { best = v; bi = n; }
    }
    sv[tid] = best; si[tid] = bi;
    __syncthreads();
    for (int off = 128; off > 0; off >>= 1) {
        if (tid < off) {
            const float v2 = sv[tid + off]; const int i2 = si[tid + off];
            if (v2 > sv[tid] || (v2 == sv[tid] && i2 < si[tid])) { sv[tid] = v2; si[tid] = i2; }
        }
        __syncthreads();
    }
    const float m = sv[0];
    const int amax = si[0];
    __syncthreads();

    float ssum = 0.f;
    for (int j = 0; j < Nn / 256; ++j) ssum += __expf(sc[tid + j * 256] - m);
    sv[tid] = ssum;
    __syncthreads();
    for (int off = 128; off > 0; off >>= 1) {
        if (tid < off) sv[tid] += sv[tid + off];
        __syncthreads();
    }
    if (tid == 0) {
        mbuf[b] = m;
        zbuf[b] = sv[0];
        out[(size_t)Bb * Dd + b] = (float)amax;
    }
}

// ---------------------------------------------------------------------------
// Partial out over n-chunks (no atomics; fixed-order accumulation)
// ---------------------------------------------------------------------------
__global__ __launch_bounds__(256) void partial_kernel(
    const float* __restrict__ V, const float* __restrict__ scores,
    const float* __restrict__ mbuf, float* __restrict__ part)
{
    __shared__ float e[CHUNK];
    const int c = blockIdx.x;
    const int b = blockIdx.y;
    const int tid = threadIdx.x;
    const float m = mbuf[b];
    if (tid < CHUNK)
        e[tid] = __expf(scores[(size_t)b * Nn + (size_t)c * CHUNK + tid] - m);
    __syncthreads();

    const float* vp = V + ((size_t)b * Nn + (size_t)c * CHUNK) * Dd + tid;
    float a0 = 0.f, a1 = 0.f, a2 = 0.f, a3 = 0.f;
    for (int n = 0; n < CHUNK; n += 4) {
        a0 = fmaf(e[n + 0], vp[(size_t)(n + 0) * Dd], a0);
        a1 = fmaf(e[n + 1], vp[(size_t)(n + 1) * Dd], a1);
        a2 = fmaf(e[n + 2], vp[(size_t)(n + 2) * Dd], a2);
        a3 = fmaf(e[n + 3], vp[(size_t)(n + 3) * Dd], a3);
    }
    part[((size_t)b * NCH + c) * Dd + tid] = ((a0 + a1) + (a2 + a3));
}

__global__ __launch_bounds__(256) void finalize_kernel(
    const float* __restrict__ part, const float* __restrict__ zbuf,
    float* __restrict__ out)
{
    const int b = blockIdx.x;
    const int tid = threadIdx.x;
    float s = 0.f;
#pragma unroll
    for (int c = 0; c < NCH; ++c) s += part[((size_t)b * NCH + c) * Dd + tid];
    out[(size_t)b * Dd + tid] = s / zbuf[b];
}

extern "C" void kernel_launch(void* const* d_in, const int* in_sizes, int n_in,
                              void* d_out, int out_size, void* d_ws, size_t ws_size,
                              hipStream_t stream) {
    const float* Q  = (const float*)d_in[0];
    const float* K  = (const float*)d_in[1];
    const float* V  = (const float*)d_in[2];
    const float* Wq = (const float*)d_in[3];
    const float* Wk = (const float*)d_in[4];
    const float* Wv = (const float*)d_in[5];
    float* out = (float*)d_out;

    // ws layout (bytes): Wh[256K] | Wl[256K] | scores[512K] | m[128] | z[128] | part[1M]
    char* wsb = (char*)d_ws;
    short* Wh     = (short*)(wsb);
    short* Wl     = (short*)(wsb + 262144);
    float* scores = (float*)(wsb + 524288);
    float* mbuf   = (float*)(wsb + 1048576);
    float* zbuf   = (float*)(wsb + 1048576 + 128);
    float* part   = (float*)(wsb + 1048576 + 256);

    prep_w_kernel<<<dim3(64), dim3(256), 0, stream>>>(Wq, Wk, Wh, Wl);
    scores_mfma_kernel<<<dim3((Bb * Nn) / 64), dim3(256), 0, stream>>>(Q, K, Wh, Wl, Wv, scores);
    softmax_reduce_kernel<<<dim3(Bb), dim3(256), 0, stream>>>(scores, mbuf, zbuf, out);
    partial_kernel<<<dim3(NCH, Bb), dim3(256), 0, stream>>>(V, scores, mbuf, part);
    finalize_kernel<<<dim3(Bb), dim3(256), 0, stream>>>(part, zbuf, out);
}

// Round 3
// 139.503 us; speedup vs baseline: 3.5306x; 1.3807x over previous
//
#include <hip/hip_runtime.h>

#define Bb 32
#define Nn 4096
#define Dd 256
#define Hh 256
#define NCH 32
#define CHUNK 128
#define NSTEPS 16   // K = 512 (Q:256 then K:256), steps of 32

typedef __attribute__((ext_vector_type(8))) short bf16x8;
typedef __attribute__((ext_vector_type(4))) float f32x4;

__device__ __forceinline__ unsigned short bf16_rtn(float x) {
    unsigned int u = __float_as_uint(x);
    u += 0x7FFF + ((u >> 16) & 1);
    return (unsigned short)(u >> 16);
}
__device__ __forceinline__ float bf16_to_f(unsigned short b) {
    return __uint_as_float(((unsigned int)b) << 16);
}
__device__ __forceinline__ float fast_tanhf(float x) {
    float e = __expf(2.0f * x);
    return 1.0f - 2.0f / (e + 1.0f);
}

// Truncation split of 8 f32 -> hi/lo bf16x8, packed with v_perm_b32.
__device__ __forceinline__ void split8_store(short* hp, short* lp, f32x4 v0, f32x4 v1) {
    float xs[8] = {v0.x, v0.y, v0.z, v0.w, v1.x, v1.y, v1.z, v1.w};
    unsigned int hu[4], lu[4];
#pragma unroll
    for (int p = 0; p < 4; ++p) {
        unsigned int u0 = __float_as_uint(xs[2 * p]);
        unsigned int u1 = __float_as_uint(xs[2 * p + 1]);
        float r0 = xs[2 * p]     - __uint_as_float(u0 & 0xFFFF0000u);
        float r1 = xs[2 * p + 1] - __uint_as_float(u1 & 0xFFFF0000u);
        hu[p] = __builtin_amdgcn_perm(u1, u0, 0x07060302u);
        lu[p] = __builtin_amdgcn_perm(__float_as_uint(r1), __float_as_uint(r0), 0x07060302u);
    }
    *(uint4*)hp = make_uint4(hu[0], hu[1], hu[2], hu[3]);
    *(uint4*)lp = make_uint4(lu[0], lu[1], lu[2], lu[3]);
}

// ---------------------------------------------------------------------------
// Prep: split Wcat = [Wq ; Wk] (H=256 rows, K=512 cols) into hi/lo bf16 blobs
// in fragment-linear order: blob[s][j][l][e] = Wcat[j*16+(l&15)][s*32+(l>>4)*8+e]
// ---------------------------------------------------------------------------
__global__ __launch_bounds__(256) void prep_w_kernel(
    const float* __restrict__ Wq, const float* __restrict__ Wk,
    short* __restrict__ Wh, short* __restrict__ Wl)
{
    const int g = blockIdx.x * 256 + threadIdx.x;      // [0, 16384)
    const int s = g >> 10;
    const int j = (g >> 6) & 15;
    const int l = g & 63;
    const int n = j * 16 + (l & 15);
    const int k = s * 32 + (l >> 4) * 8;
    const float* src = (k < 256) ? (Wq + n * 256 + k) : (Wk + n * 256 + (k - 256));
    const f32x4 v0 = *(const f32x4*)src;
    const f32x4 v1 = *(const f32x4*)(src + 4);
    float xs[8] = {v0.x, v0.y, v0.z, v0.w, v1.x, v1.y, v1.z, v1.w};
    bf16x8 h8, l8;
#pragma unroll
    for (int e = 0; e < 8; ++e) {
        unsigned short hb = bf16_rtn(xs[e]);
        float rem = xs[e] - bf16_to_f(hb);
        h8[e] = (short)hb;
        l8[e] = (short)bf16_rtn(rem);
    }
    *(bf16x8*)&Wh[(size_t)g * 8] = h8;
    *(bf16x8*)&Wl[(size_t)g * 8] = l8;
}

// ---------------------------------------------------------------------------
// Scores via split-bf16 MFMA. Block = 128 rows x 256 h, 4 waves; wave w owns
// cols [64w, 64w+64): m=8 row-tiles x n=4 col-tiles of 16x16x32.
// A staged in LDS (truncation hi/lo, double-buffered, fragment-linear);
// B frags register-double-buffered from prep blobs (L2-resident).
// ---------------------------------------------------------------------------
__global__ __launch_bounds__(256, 2) void scores_mfma_kernel(
    const float* __restrict__ Q, const float* __restrict__ Kmat,
    const short* __restrict__ Wh, const short* __restrict__ Wl,
    const float* __restrict__ Wv, float* __restrict__ scores)
{
    __shared__ short Ah[2][4096];      // [buf][(m*64+lane)*8+e] hi  (16 KB)
    __shared__ short Al[2][4096];      // lo                        (16 KB)
    __shared__ float red[4][128];

    const int tid = threadIdx.x;
    const int lane = tid & 63;
    const int wave = tid >> 6;
    const size_t row0 = (size_t)blockIdx.x * 128;

    f32x4 acc[8][4];
#pragma unroll
    for (int m = 0; m < 8; ++m)
#pragma unroll
        for (int n = 0; n < 4; ++n) acc[m][n] = (f32x4){0.f, 0.f, 0.f, 0.f};

    float wv[4];
#pragma unroll
    for (int n = 0; n < 4; ++n) wv[n] = Wv[wave * 64 + n * 16 + (lane & 15)];

    // staging: thread t owns frag slots t and t+256. slot s: m=s>>6, l=s&63,
    // row = m*16+(l&15), k-chunk = ((l>>4)&3)*8. 128B-coalesced global reads.
    const int r_s0 = ((tid >> 6) << 4) + (tid & 15);
    const int r_s1 = r_s0 + 64;
    const int k_s0 = ((tid >> 4) & 3) * 8;

    f32x4 a0, a1, a2, a3;              // in-flight A (one step ahead)

    auto issue_a = [&](int s) {
        const float* Asrc = (s < 8) ? Q : Kmat;
        const int kb = (s & 7) * 32 + k_s0;
        const float* p0 = Asrc + (row0 + r_s0) * Dd + kb;
        const float* p1 = Asrc + (row0 + r_s1) * Dd + kb;
        a0 = *(const f32x4*)p0; a1 = *(const f32x4*)(p0 + 4);
        a2 = *(const f32x4*)p1; a3 = *(const f32x4*)(p1 + 4);
    };
    auto issue_b = [&](int s, bf16x8 (&bh)[4], bf16x8 (&bl)[4]) {
#pragma unroll
        for (int n = 0; n < 4; ++n) {
            const size_t bo = ((size_t)(s * 16 + wave * 4 + n) * 64 + lane) * 8;
            bh[n] = *(const bf16x8*)(Wh + bo);
            bl[n] = *(const bf16x8*)(Wl + bo);
        }
    };
    auto split_store = [&](int buf) {
        split8_store(&Ah[buf][tid * 8], &Al[buf][tid * 8], a0, a1);
        split8_store(&Ah[buf][(tid + 256) * 8], &Al[buf][(tid + 256) * 8], a2, a3);
    };

    bf16x8 BAh[4], BAl[4], BBh[4], BBl[4];

    auto do_step = [&](int s, int cur, bf16x8 (&buh)[4], bf16x8 (&bul)[4],
                       bf16x8 (&bfh)[4], bf16x8 (&bfl)[4]) {
        const int sn = s + 1;
        if (sn < NSTEPS) {
            issue_a(sn);               // HBM loads, consumed at step bottom
            issue_b(sn, bfh, bfl);     // L2 loads, consumed next step
        }
        __builtin_amdgcn_s_setprio(1);
#pragma unroll
        for (int m = 0; m < 8; ++m) {
            const bf16x8 ahm = *(const bf16x8*)&Ah[cur][(m * 64 + lane) * 8];
            const bf16x8 alm = *(const bf16x8*)&Al[cur][(m * 64 + lane) * 8];
#pragma unroll
            for (int n = 0; n < 4; ++n) {
                acc[m][n] = __builtin_amdgcn_mfma_f32_16x16x32_bf16(ahm, buh[n], acc[m][n], 0, 0, 0);
                acc[m][n] = __builtin_amdgcn_mfma_f32_16x16x32_bf16(alm, buh[n], acc[m][n], 0, 0, 0);
                acc[m][n] = __builtin_amdgcn_mfma_f32_16x16x32_bf16(ahm, bul[n], acc[m][n], 0, 0, 0);
            }
        }
        __builtin_amdgcn_s_setprio(0);
        if (sn < NSTEPS) split_store(cur ^ 1);
        __syncthreads();
    };

    // prologue: stage step 0 (A -> LDS buf0, B -> BA regs)
    issue_a(0);
    issue_b(0, BAh, BAl);
    split_store(0);
    __syncthreads();                   // drains vmcnt -> BA guaranteed arrived

    for (int s2 = 0; s2 < NSTEPS / 2; ++s2) {
        do_step(2 * s2,     0, BAh, BAl, BBh, BBl);
        do_step(2 * s2 + 1, 1, BBh, BBl, BAh, BAl);
    }

    // Epilogue: score_row += Wv[col] * tanh(acc). C/D: col=lane&15,
    // row = m*16 + (lane>>4)*4 + r. Fixed-order reduce -> deterministic.
    const int q = lane >> 4;
    float rp[8][4];
#pragma unroll
    for (int m = 0; m < 8; ++m)
#pragma unroll
        for (int r = 0; r < 4; ++r) {
            float v = 0.f;
#pragma unroll
            for (int n = 0; n < 4; ++n)
                v += wv[n] * fast_tanhf(acc[m][n][r]);
            rp[m][r] = v;
        }
#pragma unroll
    for (int mask = 1; mask <= 8; mask <<= 1)
#pragma unroll
        for (int m = 0; m < 8; ++m)
#pragma unroll
            for (int r = 0; r < 4; ++r)
                rp[m][r] += __shfl_xor(rp[m][r], mask, 64);

    if ((lane & 15) == 0) {
#pragma unroll
        for (int m = 0; m < 8; ++m)
#pragma unroll
            for (int r = 0; r < 4; ++r)
                red[wave][m * 16 + q * 4 + r] = rp[m][r];
    }
    __syncthreads();
    if (tid < 128)
        scores[row0 + tid] = (red[0][tid] + red[1][tid]) + (red[2][tid] + red[3][tid]);
}

// ---------------------------------------------------------------------------
// Per-b max + first-index argmax + sum(exp). Writes argmax output.
// ---------------------------------------------------------------------------
__global__ __launch_bounds__(256) void softmax_reduce_kernel(
    const float* __restrict__ scores, float* __restrict__ mbuf,
    float* __restrict__ zbuf, float* __restrict__ out)
{
    __shared__ float sv[256];
    __shared__ int si[256];
    const int b = blockIdx.x;
    const int tid = threadIdx.x;
    const float* sc = scores + (size_t)b * Nn;

    float best = -1e30f; int bi = 0;
    for (int j = 0; j < Nn / 256; ++j) {
        const int n = tid + j * 256;
        const float v = sc[n];
        if (v > best) { best = v; bi = n; }
    }
    sv[tid] = best; si[tid] = bi;
    __syncthreads();
    for (int off = 128; off > 0; off >>= 1) {
        if (tid < off) {
            const float v2 = sv[tid + off]; const int i2 = si[tid + off];
            if (v2 > sv[tid] || (v2 == sv[tid] && i2 < si[tid])) { sv[tid] = v2; si[tid] = i2; }
        }
        __syncthreads();
    }
    const float m = sv[0];
    const int amax = si[0];
    __syncthreads();

    float ssum = 0.f;
    for (int j = 0; j < Nn / 256; ++j) ssum += __expf(sc[tid + j * 256] - m);
    sv[tid] = ssum;
    __syncthreads();
    for (int off = 128; off > 0; off >>= 1) {
        if (tid < off) sv[tid] += sv[tid + off];
        __syncthreads();
    }
    if (tid == 0) {
        mbuf[b] = m;
        zbuf[b] = sv[0];
        out[(size_t)Bb * Dd + b] = (float)amax;
    }
}

// ---------------------------------------------------------------------------
// Partial out over n-chunks (no atomics; fixed-order accumulation)
// ---------------------------------------------------------------------------
__global__ __launch_bounds__(256) void partial_kernel(
    const float* __restrict__ V, const float* __restrict__ scores,
    const float* __restrict__ mbuf, float* __restrict__ part)
{
    __shared__ float e[CHUNK];
    const int c = blockIdx.x;
    const int b = blockIdx.y;
    const int tid = threadIdx.x;
    const float m = mbuf[b];
    if (tid < CHUNK)
        e[tid] = __expf(scores[(size_t)b * Nn + (size_t)c * CHUNK + tid] - m);
    __syncthreads();

    const float* vp = V + ((size_t)b * Nn + (size_t)c * CHUNK) * Dd + tid;
    float a0 = 0.f, a1 = 0.f, a2 = 0.f, a3 = 0.f;
    for (int n = 0; n < CHUNK; n += 4) {
        a0 = fmaf(e[n + 0], vp[(size_t)(n + 0) * Dd], a0);
        a1 = fmaf(e[n + 1], vp[(size_t)(n + 1) * Dd], a1);
        a2 = fmaf(e[n + 2], vp[(size_t)(n + 2) * Dd], a2);
        a3 = fmaf(e[n + 3], vp[(size_t)(n + 3) * Dd], a3);
    }
    part[((size_t)b * NCH + c) * Dd + tid] = ((a0 + a1) + (a2 + a3));
}

__global__ __launch_bounds__(256) void finalize_kernel(
    const float* __restrict__ part, const float* __restrict__ zbuf,
    float* __restrict__ out)
{
    const int b = blockIdx.x;
    const int tid = threadIdx.x;
    float s = 0.f;
#pragma unroll
    for (int c = 0; c < NCH; ++c) s += part[((size_t)b * NCH + c) * Dd + tid];
    out[(size_t)b * Dd + tid] = s / zbuf[b];
}

extern "C" void kernel_launch(void* const* d_in, const int* in_sizes, int n_in,
                              void* d_out, int out_size, void* d_ws, size_t ws_size,
                              hipStream_t stream) {
    const float* Q  = (const float*)d_in[0];
    const float* K  = (const float*)d_in[1];
    const float* V  = (const float*)d_in[2];
    const float* Wq = (const float*)d_in[3];
    const float* Wk = (const float*)d_in[4];
    const float* Wv = (const float*)d_in[5];
    float* out = (float*)d_out;

    // ws layout (bytes): Wh[256K] | Wl[256K] | scores[512K] | m[128] | z[128] | part[1M]
    char* wsb = (char*)d_ws;
    short* Wh     = (short*)(wsb);
    short* Wl     = (short*)(wsb + 262144);
    float* scores = (float*)(wsb + 524288);
    float* mbuf   = (float*)(wsb + 1048576);
    float* zbuf   = (float*)(wsb + 1048576 + 128);
    float* part   = (float*)(wsb + 1048576 + 256);

    prep_w_kernel<<<dim3(64), dim3(256), 0, stream>>>(Wq, Wk, Wh, Wl);
    scores_mfma_kernel<<<dim3((Bb * Nn) / 128), dim3(256), 0, stream>>>(Q, K, Wh, Wl, Wv, scores);
    softmax_reduce_kernel<<<dim3(Bb), dim3(256), 0, stream>>>(scores, mbuf, zbuf, out);
    partial_kernel<<<dim3(NCH, Bb), dim3(256), 0, stream>>>(V, scores, mbuf, part);
    finalize_kernel<<<dim3(Bb), dim3(256), 0, stream>>>(part, zbuf, out);
}

// Round 4
// 132.527 us; speedup vs baseline: 3.7165x; 1.0526x over previous
//
#include <hip/hip_runtime.h>

#define Bb 32
#define Nn 4096
#define Dd 256
#define Hh 256
#define NCH 32
#define CHUNK 128
#define NSTEPS 16   // K = 512 (Q:256 then K:256), steps of 32

typedef __attribute__((ext_vector_type(8))) short bf16x8;
typedef __attribute__((ext_vector_type(4))) float f32x4;

__device__ __forceinline__ unsigned short bf16_rtn(float x) {
    unsigned int u = __float_as_uint(x);
    u += 0x7FFF + ((u >> 16) & 1);
    return (unsigned short)(u >> 16);
}
__device__ __forceinline__ float bf16_to_f(unsigned short b) {
    return __uint_as_float(((unsigned int)b) << 16);
}
__device__ __forceinline__ float fast_tanhf(float x) {
    float e = __expf(2.0f * x);
    return 1.0f - 2.0f / (e + 1.0f);
}

// Truncation split of 8 f32 -> hi/lo bf16x8, packed with v_perm_b32.
__device__ __forceinline__ void split8_store(short* hp, short* lp, f32x4 v0, f32x4 v1) {
    float xs[8] = {v0.x, v0.y, v0.z, v0.w, v1.x, v1.y, v1.z, v1.w};
    unsigned int hu[4], lu[4];
#pragma unroll
    for (int p = 0; p < 4; ++p) {
        unsigned int u0 = __float_as_uint(xs[2 * p]);
        unsigned int u1 = __float_as_uint(xs[2 * p + 1]);
        float r0 = xs[2 * p]     - __uint_as_float(u0 & 0xFFFF0000u);
        float r1 = xs[2 * p + 1] - __uint_as_float(u1 & 0xFFFF0000u);
        hu[p] = __builtin_amdgcn_perm(u1, u0, 0x07060302u);
        lu[p] = __builtin_amdgcn_perm(__float_as_uint(r1), __float_as_uint(r0), 0x07060302u);
    }
    *(uint4*)hp = make_uint4(hu[0], hu[1], hu[2], hu[3]);
    *(uint4*)lp = make_uint4(lu[0], lu[1], lu[2], lu[3]);
}

// ---------------------------------------------------------------------------
// Prep: split Wcat = [Wq ; Wk] (H=256 rows, K=512 cols) into hi/lo bf16 blobs
// in fragment-linear order: blob[s][j][l][e] = Wcat[j*16+(l&15)][s*32+(l>>4)*8+e]
// ---------------------------------------------------------------------------
__global__ __launch_bounds__(256) void prep_w_kernel(
    const float* __restrict__ Wq, const float* __restrict__ Wk,
    short* __restrict__ Wh, short* __restrict__ Wl)
{
    const int g = blockIdx.x * 256 + threadIdx.x;      // [0, 16384)
    const int s = g >> 10;
    const int j = (g >> 6) & 15;
    const int l = g & 63;
    const int n = j * 16 + (l & 15);
    const int k = s * 32 + (l >> 4) * 8;
    const float* src = (k < 256) ? (Wq + n * 256 + k) : (Wk + n * 256 + (k - 256));
    const f32x4 v0 = *(const f32x4*)src;
    const f32x4 v1 = *(const f32x4*)(src + 4);
    float xs[8] = {v0.x, v0.y, v0.z, v0.w, v1.x, v1.y, v1.z, v1.w};
    bf16x8 h8, l8;
#pragma unroll
    for (int e = 0; e < 8; ++e) {
        unsigned short hb = bf16_rtn(xs[e]);
        float rem = xs[e] - bf16_to_f(hb);
        h8[e] = (short)hb;
        l8[e] = (short)bf16_rtn(rem);
    }
    *(bf16x8*)&Wh[(size_t)g * 8] = h8;
    *(bf16x8*)&Wl[(size_t)g * 8] = l8;
}

// ---------------------------------------------------------------------------
// Scores via split-bf16 MFMA. Block = 128 rows x 256 h, 4 waves; wave w owns
// cols [64w, 64w+64): m=8 x n=4 tiles of 16x16x32.
// A pipeline depth 2: loads for s+2 issued at step s (P/Q reg sets, parity);
// split_store for s+1 at step s (regs arrived a full step ago -> wait-free);
// LDS triple-buffered. B single-buffered from L2-resident prep blobs.
// ---------------------------------------------------------------------------
__global__ __launch_bounds__(256, 2) void scores_mfma_kernel(
    const float* __restrict__ Q, const float* __restrict__ Kmat,
    const short* __restrict__ Wh, const short* __restrict__ Wl,
    const float* __restrict__ Wv, float* __restrict__ scores)
{
    __shared__ short Ah[3][4096];      // [buf][(m*64+lane)*8+e] hi  (24 KB)
    __shared__ short Al[3][4096];      // lo                         (24 KB)
    __shared__ float red[4][128];

    const int tid = threadIdx.x;
    const int lane = tid & 63;
    const int wave = tid >> 6;
    const size_t row0 = (size_t)blockIdx.x * 128;

    f32x4 acc[8][4];
#pragma unroll
    for (int m = 0; m < 8; ++m)
#pragma unroll
        for (int n = 0; n < 4; ++n) acc[m][n] = (f32x4){0.f, 0.f, 0.f, 0.f};

    float wv[4];
#pragma unroll
    for (int n = 0; n < 4; ++n) wv[n] = Wv[wave * 64 + n * 16 + (lane & 15)];

    // staging: thread t owns frag slots t and t+256. slot s: m=s>>6, l=s&63,
    // row = m*16+(l&15), k-chunk = ((l>>4)&3)*8. 128B-coalesced global reads.
    const int r_s0 = ((tid >> 6) << 4) + (tid & 15);
    const int r_s1 = r_s0 + 64;
    const int k_s0 = ((tid >> 4) & 3) * 8;

    // two in-flight A register sets (P: even-step issue, Q: odd-step issue)
    f32x4 pA0, pA1, pA2, pA3;
    f32x4 qA0, qA1, qA2, qA3;
    bf16x8 bh[4], bl[4];

    auto issue_aP = [&](int s) {
        if (s >= NSTEPS) return;
        const float* Asrc = (s < 8) ? Q : Kmat;
        const int kb = (s & 7) * 32 + k_s0;
        const float* p0 = Asrc + (row0 + r_s0) * Dd + kb;
        const float* p1 = Asrc + (row0 + r_s1) * Dd + kb;
        pA0 = *(const f32x4*)p0; pA1 = *(const f32x4*)(p0 + 4);
        pA2 = *(const f32x4*)p1; pA3 = *(const f32x4*)(p1 + 4);
    };
    auto issue_aQ = [&](int s) {
        if (s >= NSTEPS) return;
        const float* Asrc = (s < 8) ? Q : Kmat;
        const int kb = (s & 7) * 32 + k_s0;
        const float* p0 = Asrc + (row0 + r_s0) * Dd + kb;
        const float* p1 = Asrc + (row0 + r_s1) * Dd + kb;
        qA0 = *(const f32x4*)p0; qA1 = *(const f32x4*)(p0 + 4);
        qA2 = *(const f32x4*)p1; qA3 = *(const f32x4*)(p1 + 4);
    };
    auto issue_b = [&](int s) {
#pragma unroll
        for (int n = 0; n < 4; ++n) {
            const size_t bo = ((size_t)(s * 16 + wave * 4 + n) * 64 + lane) * 8;
            bh[n] = *(const bf16x8*)(Wh + bo);
            bl[n] = *(const bf16x8*)(Wl + bo);
        }
    };
    auto splitP = [&](int buf) {
        split8_store(&Ah[buf][tid * 8], &Al[buf][tid * 8], pA0, pA1);
        split8_store(&Ah[buf][(tid + 256) * 8], &Al[buf][(tid + 256) * 8], pA2, pA3);
    };
    auto splitQ = [&](int buf) {
        split8_store(&Ah[buf][tid * 8], &Al[buf][tid * 8], qA0, qA1);
        split8_store(&Ah[buf][(tid + 256) * 8], &Al[buf][(tid + 256) * 8], qA2, qA3);
    };
    auto cluster = [&](int rb) {
        const short* ahb = &Ah[rb][0];
        const short* alb = &Al[rb][0];
        __builtin_amdgcn_s_setprio(1);
#pragma unroll
        for (int m = 0; m < 8; ++m) {
            const bf16x8 ahm = *(const bf16x8*)&ahb[(m * 64 + lane) * 8];
            const bf16x8 alm = *(const bf16x8*)&alb[(m * 64 + lane) * 8];
#pragma unroll
            for (int n = 0; n < 4; ++n) {
                acc[m][n] = __builtin_amdgcn_mfma_f32_16x16x32_bf16(ahm, bh[n], acc[m][n], 0, 0, 0);
                acc[m][n] = __builtin_amdgcn_mfma_f32_16x16x32_bf16(alm, bh[n], acc[m][n], 0, 0, 0);
                acc[m][n] = __builtin_amdgcn_mfma_f32_16x16x32_bf16(ahm, bl[n], acc[m][n], 0, 0, 0);
            }
        }
        __builtin_amdgcn_s_setprio(0);
    };

    // prologue: P<-step0, Q<-step1; split step0 into LDS[0] (one-time wait)
    issue_aP(0);
    issue_aQ(1);
    splitP(0);
    __syncthreads();

    // steady state: at step s, read LDS[s%3]; split step s+1 (regs loaded at
    // s-1) into LDS[(s+1)%3]; issue loads for s+2 into the freed reg set.
    int rb = 0;
    for (int s2 = 0; s2 < NSTEPS / 2; ++s2) {
        const int s = 2 * s2;
        // even step: consume LDS[rb]; split Q (step s+1); issue P <- s+2
        issue_b(s);
        issue_aP(s + 2);
        cluster(rb);
        if (s + 1 < NSTEPS) splitQ(rb == 2 ? 0 : rb + 1);
        __syncthreads();
        // odd step: consume LDS[rb+1]; split P (step s+2); issue Q <- s+3
        issue_b(s + 1);
        issue_aQ(s + 3);
        cluster(rb == 2 ? 0 : rb + 1);
        if (s + 2 < NSTEPS) splitP(rb >= 1 ? rb - 1 : rb + 2);
        __syncthreads();
        rb = (rb >= 1) ? rb - 1 : rb + 2;   // rb = (rb+2)%3
    }

    // Epilogue: score_row += Wv[col] * tanh(acc). C/D: col=lane&15,
    // row = m*16 + (lane>>4)*4 + r. Fixed-order reduce -> deterministic.
    const int q = lane >> 4;
    float rp[8][4];
#pragma unroll
    for (int m = 0; m < 8; ++m)
#pragma unroll
        for (int r = 0; r < 4; ++r) {
            float v = 0.f;
#pragma unroll
            for (int n = 0; n < 4; ++n)
                v += wv[n] * fast_tanhf(acc[m][n][r]);
            rp[m][r] = v;
        }
#pragma unroll
    for (int mask = 1; mask <= 8; mask <<= 1)
#pragma unroll
        for (int m = 0; m < 8; ++m)
#pragma unroll
            for (int r = 0; r < 4; ++r)
                rp[m][r] += __shfl_xor(rp[m][r], mask, 64);

    if ((lane & 15) == 0) {
#pragma unroll
        for (int m = 0; m < 8; ++m)
#pragma unroll
            for (int r = 0; r < 4; ++r)
                red[wave][m * 16 + q * 4 + r] = rp[m][r];
    }
    __syncthreads();
    if (tid < 128)
        scores[row0 + tid] = (red[0][tid] + red[1][tid]) + (red[2][tid] + red[3][tid]);
}

// ---------------------------------------------------------------------------
// Per-b max + first-index argmax + sum(exp). Writes argmax output.
// ---------------------------------------------------------------------------
__global__ __launch_bounds__(256) void softmax_reduce_kernel(
    const float* __restrict__ scores, float* __restrict__ mbuf,
    float* __restrict__ zbuf, float* __restrict__ out)
{
    __shared__ float sv[256];
    __shared__ int si[256];
    const int b = blockIdx.x;
    const int tid = threadIdx.x;
    const float* sc = scores + (size_t)b * Nn;

    float best = -1e30f; int bi = 0;
    for (int j = 0; j < Nn / 256; ++j) {
        const int n = tid + j * 256;
        const float v = sc[n];
        if (v > best) { best = v; bi = n; }
    }
    sv[tid] = best; si[tid] = bi;
    __syncthreads();
    for (int off = 128; off > 0; off >>= 1) {
        if (tid < off) {
            const float v2 = sv[tid + off]; const int i2 = si[tid + off];
            if (v2 > sv[tid] || (v2 == sv[tid] && i2 < si[tid])) { sv[tid] = v2; si[tid] = i2; }
        }
        __syncthreads();
    }
    const float m = sv[0];
    const int amax = si[0];
    __syncthreads();

    float ssum = 0.f;
    for (int j = 0; j < Nn / 256; ++j) ssum += __expf(sc[tid + j * 256] - m);
    sv[tid] = ssum;
    __syncthreads();
    for (int off = 128; off > 0; off >>= 1) {
        if (tid < off) sv[tid] += sv[tid + off];
        __syncthreads();
    }
    if (tid == 0) {
        mbuf[b] = m;
        zbuf[b] = sv[0];
        out[(size_t)Bb * Dd + b] = (float)amax;
    }
}

// ---------------------------------------------------------------------------
// Partial out over n-chunks (no atomics; fixed-order accumulation)
// ---------------------------------------------------------------------------
__global__ __launch_bounds__(256) void partial_kernel(
    const float* __restrict__ V, const float* __restrict__ scores,
    const float* __restrict__ mbuf, float* __restrict__ part)
{
    __shared__ float e[CHUNK];
    const int c = blockIdx.x;
    const int b = blockIdx.y;
    const int tid = threadIdx.x;
    const float m = mbuf[b];
    if (tid < CHUNK)
        e[tid] = __expf(scores[(size_t)b * Nn + (size_t)c * CHUNK + tid] - m);
    __syncthreads();

    const float* vp = V + ((size_t)b * Nn + (size_t)c * CHUNK) * Dd + tid;
    float a0 = 0.f, a1 = 0.f, a2 = 0.f, a3 = 0.f;
    for (int n = 0; n < CHUNK; n += 4) {
        a0 = fmaf(e[n + 0], vp[(size_t)(n + 0) * Dd], a0);
        a1 = fmaf(e[n + 1], vp[(size_t)(n + 1) * Dd], a1);
        a2 = fmaf(e[n + 2], vp[(size_t)(n + 2) * Dd], a2);
        a3 = fmaf(e[n + 3], vp[(size_t)(n + 3) * Dd], a3);
    }
    part[((size_t)b * NCH + c) * Dd + tid] = ((a0 + a1) + (a2 + a3));
}

__global__ __launch_bounds__(256) void finalize_kernel(
    const float* __restrict__ part, const float* __restrict__ zbuf,
    float* __restrict__ out)
{
    const int b = blockIdx.x;
    const int tid = threadIdx.x;
    float s = 0.f;
#pragma unroll
    for (int c = 0; c < NCH; ++c) s += part[((size_t)b * NCH + c) * Dd + tid];
    out[(size_t)b * Dd + tid] = s / zbuf[b];
}

extern "C" void kernel_launch(void* const* d_in, const int* in_sizes, int n_in,
                              void* d_out, int out_size, void* d_ws, size_t ws_size,
                              hipStream_t stream) {
    const float* Q  = (const float*)d_in[0];
    const float* K  = (const float*)d_in[1];
    const float* V  = (const float*)d_in[2];
    const float* Wq = (const float*)d_in[3];
    const float* Wk = (const float*)d_in[4];
    const float* Wv = (const float*)d_in[5];
    float* out = (float*)d_out;

    // ws layout (bytes): Wh[256K] | Wl[256K] | scores[512K] | m[128] | z[128] | part[1M]
    char* wsb = (char*)d_ws;
    short* Wh     = (short*)(wsb);
    short* Wl     = (short*)(wsb + 262144);
    float* scores = (float*)(wsb + 524288);
    float* mbuf   = (float*)(wsb + 1048576);
    float* zbuf   = (float*)(wsb + 1048576 + 128);
    float* part   = (float*)(wsb + 1048576 + 256);

    prep_w_kernel<<<dim3(64), dim3(256), 0, stream>>>(Wq, Wk, Wh, Wl);
    scores_mfma_kernel<<<dim3((Bb * Nn) / 128), dim3(256), 0, stream>>>(Q, K, Wh, Wl, Wv, scores);
    softmax_reduce_kernel<<<dim3(Bb), dim3(256), 0, stream>>>(scores, mbuf, zbuf, out);
    partial_kernel<<<dim3(NCH, Bb), dim3(256), 0, stream>>>(V, scores, mbuf, part);
    finalize_kernel<<<dim3(Bb), dim3(256), 0, stream>>>(part, zbuf, out);
}